// Round 1
// baseline (5483.177 us; speedup 1.0000x reference)
//
#include <hip/hip_runtime.h>
#include <hip/hip_bf16.h>

#define F_IN  512
#define F_HID 16
#define F_OUT 40

typedef __attribute__((ext_vector_type(4))) float f32x4;
typedef __attribute__((ext_vector_type(8))) short s16x8;

// ---------------- degree / normalization ----------------

__global__ void k_init_deg(float* __restrict__ deg, int n) {
    int i = blockIdx.x * 256 + threadIdx.x;
    if (i < n) deg[i] = 1.0f;   // self-loop contributes 1 to every node's degree
}

__global__ void k_count_deg(const int* __restrict__ col, float* __restrict__ deg, int nE) {
    int e = blockIdx.x * 256 + threadIdx.x;
    if (e < nE) atomicAdd(&deg[col[e]], 1.0f);   // float adds of 1.0 are exact -> deterministic
}

__global__ void k_dinv(float* __restrict__ deg, int n) {
    int i = blockIdx.x * 256 + threadIdx.x;
    if (i < n) deg[i] = rsqrtf(deg[i]);          // deg >= 1 always (self-loops)
}

// ---------------- h1 = x @ W1  (bf16 MFMA, W1 fragments register-resident) ----------------
// A-frag (16x32 bf16): lane l holds row m=l&15, k=(l>>4)*8+i
// B-frag (32x16 bf16): lane l holds col n=l&15, k=(l>>4)*8+i
// D (16x16 f32):       lane l holds col n=l&15, row=(l>>4)*4+p   [m89-verified]
__global__ __launch_bounds__(256) void k_xw1(const float* __restrict__ x,
                                             const float* __restrict__ W1,
                                             float* __restrict__ h1, int n_tiles) {
    int lane = threadIdx.x & 63;
    int wid  = threadIdx.x >> 6;
    int m = lane & 15;
    int g = lane >> 4;

    // Load + convert all 16 B-fragments of W1 (512x16) once. 64 VGPRs.
    s16x8 bf[16];
#pragma unroll
    for (int kb = 0; kb < 16; ++kb) {
        union { s16x8 s; unsigned u[4]; } bu;
#pragma unroll
        for (int p = 0; p < 4; ++p) {
            int k0 = kb * 32 + g * 8 + p * 2;
            float lo = W1[(k0 + 0) * F_HID + m];
            float hi = W1[(k0 + 1) * F_HID + m];
            unsigned pk;
            asm("v_cvt_pk_bf16_f32 %0, %1, %2" : "=v"(pk) : "v"(lo), "v"(hi));
            bu.u[p] = pk;
        }
        bf[kb] = bu.s;
    }

    int tile = blockIdx.x * 4 + wid;
    if (tile >= n_tiles) return;

    const float* xr = x + (size_t)(tile * 16 + m) * F_IN + g * 8;
    f32x4 acc = {0.f, 0.f, 0.f, 0.f};
#pragma unroll
    for (int kb = 0; kb < 16; ++kb) {
        f32x4 xa = *(const f32x4*)(xr + kb * 32);
        f32x4 xb = *(const f32x4*)(xr + kb * 32 + 4);
        union { s16x8 s; unsigned u[4]; } au;
        asm("v_cvt_pk_bf16_f32 %0, %1, %2" : "=v"(au.u[0]) : "v"(xa.x), "v"(xa.y));
        asm("v_cvt_pk_bf16_f32 %0, %1, %2" : "=v"(au.u[1]) : "v"(xa.z), "v"(xa.w));
        asm("v_cvt_pk_bf16_f32 %0, %1, %2" : "=v"(au.u[2]) : "v"(xb.x), "v"(xb.y));
        asm("v_cvt_pk_bf16_f32 %0, %1, %2" : "=v"(au.u[3]) : "v"(xb.z), "v"(xb.w));
        acc = __builtin_amdgcn_mfma_f32_16x16x32_bf16(au.s, bf[kb], acc, 0, 0, 0);
    }
#pragma unroll
    for (int p = 0; p < 4; ++p) {
        h1[(size_t)(tile * 16 + g * 4 + p) * F_HID + m] = acc[p];
    }
}

// ---------------- agg init with self-loop term: agg[n][:] = dinv[n]^2 * src[n][:] ----------------
__global__ void k_self(const float* __restrict__ dinv, const float* __restrict__ src,
                       float* __restrict__ agg, int n4) {
    int t = blockIdx.x * 256 + threadIdx.x;
    if (t >= n4) return;
    int nidx = t >> 2;
    float di = dinv[nidx];
    f32x4 v = ((const f32x4*)src)[t];
    ((f32x4*)agg)[t] = v * (di * di);
}

// ---------------- edge scatter: agg[col] += dinv[row]*dinv[col] * src[row][:] ----------------
__global__ void k_scatter(const int* __restrict__ row, const int* __restrict__ colv,
                          const float* __restrict__ dinv, const float* __restrict__ src,
                          float* __restrict__ agg, int nE) {
    int e = blockIdx.x * 256 + threadIdx.x;
    if (e >= nE) return;
    int r = row[e], c = colv[e];
    float nrm = dinv[r] * dinv[c];
    const f32x4* s = (const f32x4*)(src + (size_t)r * F_HID);
    f32x4 a = s[0], b = s[1], cc = s[2], d = s[3];
    float* ap = agg + (size_t)c * F_HID;
    atomicAdd(ap + 0,  nrm * a.x);  atomicAdd(ap + 1,  nrm * a.y);
    atomicAdd(ap + 2,  nrm * a.z);  atomicAdd(ap + 3,  nrm * a.w);
    atomicAdd(ap + 4,  nrm * b.x);  atomicAdd(ap + 5,  nrm * b.y);
    atomicAdd(ap + 6,  nrm * b.z);  atomicAdd(ap + 7,  nrm * b.w);
    atomicAdd(ap + 8,  nrm * cc.x); atomicAdd(ap + 9,  nrm * cc.y);
    atomicAdd(ap + 10, nrm * cc.z); atomicAdd(ap + 11, nrm * cc.w);
    atomicAdd(ap + 12, nrm * d.x);  atomicAdd(ap + 13, nrm * d.y);
    atomicAdd(ap + 14, nrm * d.z);  atomicAdd(ap + 15, nrm * d.w);
}

// ---------------- hrelu = relu(agg1 + b1); agg2_init = dinv^2 * hrelu (in-place over agg1) ----------------
__global__ void k_relu2(const float* __restrict__ b1, const float* __restrict__ dinv,
                        float* __restrict__ agg, float* __restrict__ hrelu, int n4) {
    int t = blockIdx.x * 256 + threadIdx.x;
    if (t >= n4) return;
    int nidx = t >> 2, q = t & 3;
    float di = dinv[nidx];
    f32x4 a = ((const f32x4*)agg)[t];
    f32x4 bb = ((const f32x4*)b1)[q];
    f32x4 h;
    h.x = fmaxf(a.x + bb.x, 0.f);
    h.y = fmaxf(a.y + bb.y, 0.f);
    h.z = fmaxf(a.z + bb.z, 0.f);
    h.w = fmaxf(a.w + bb.w, 0.f);
    ((f32x4*)hrelu)[t] = h;
    ((f32x4*)agg)[t] = h * (di * di);
}

// ---------------- out = log_softmax(agg2 @ W2 + b2) ----------------
__global__ __launch_bounds__(256) void k_final(const float* __restrict__ agg2,
                                               const float* __restrict__ W2,
                                               const float* __restrict__ b2,
                                               float* __restrict__ out, int n) {
    __shared__ float W2s[F_HID * F_OUT];
    __shared__ float b2s[F_OUT];
    for (int i = threadIdx.x; i < F_HID * F_OUT; i += 256) W2s[i] = W2[i];
    if (threadIdx.x < F_OUT) b2s[threadIdx.x] = b2[threadIdx.x];
    __syncthreads();

    int nidx = blockIdx.x * 256 + threadIdx.x;
    if (nidx >= n) return;

    float a[F_HID];
    const f32x4* ap = (const f32x4*)(agg2 + (size_t)nidx * F_HID);
#pragma unroll
    for (int q = 0; q < 4; ++q) {
        f32x4 v = ap[q];
        a[q * 4 + 0] = v.x; a[q * 4 + 1] = v.y; a[q * 4 + 2] = v.z; a[q * 4 + 3] = v.w;
    }

    float o[F_OUT];
#pragma unroll
    for (int j = 0; j < F_OUT; ++j) {
        float acc = b2s[j];
#pragma unroll
        for (int k = 0; k < F_HID; ++k) acc += a[k] * W2s[k * F_OUT + j];
        o[j] = acc;
    }
    float mx = o[0];
#pragma unroll
    for (int j = 1; j < F_OUT; ++j) mx = fmaxf(mx, o[j]);
    float s = 0.f;
#pragma unroll
    for (int j = 0; j < F_OUT; ++j) s += __expf(o[j] - mx);
    float lse = mx + __logf(s);

    float* op = out + (size_t)nidx * F_OUT;
#pragma unroll
    for (int j = 0; j < F_OUT; ++j) op[j] = o[j] - lse;
}

// ---------------- launcher ----------------

extern "C" void kernel_launch(void* const* d_in, const int* in_sizes, int n_in,
                              void* d_out, int out_size, void* d_ws, size_t ws_size,
                              hipStream_t stream) {
    const float* x  = (const float*)d_in[0];
    const int*   ei = (const int*)d_in[1];
    const float* W1 = (const float*)d_in[2];
    const float* b1 = (const float*)d_in[3];
    const float* W2 = (const float*)d_in[4];
    const float* b2 = (const float*)d_in[5];
    float* out = (float*)d_out;

    const int N = out_size / F_OUT;       // 100000
    const int E = in_sizes[1] / 2;        // 3200000
    const int* row = ei;                  // sources
    const int* col = ei + E;              // targets

    float* ws   = (float*)d_ws;
    float* dinv = ws;                     // N floats (deg, then dinv in place)
    float* B1   = ws + N;                 // N*16: h1, then hrelu
    float* B2   = B1 + (size_t)N * F_HID; // N*16: agg1, then agg2

    int nbN  = (N + 255) / 256;
    int nbE  = (E + 255) / 256;
    int nbN4 = (N * 4 + 255) / 256;
    int tiles = (N + 15) / 16;
    int nbT  = (tiles + 3) / 4;

    k_init_deg<<<nbN, 256, 0, stream>>>(dinv, N);
    k_count_deg<<<nbE, 256, 0, stream>>>(col, dinv, E);
    k_dinv<<<nbN, 256, 0, stream>>>(dinv, N);

    k_xw1<<<nbT, 256, 0, stream>>>(x, W1, B1, tiles);

    k_self<<<nbN4, 256, 0, stream>>>(dinv, B1, B2, N * 4);
    k_scatter<<<nbE, 256, 0, stream>>>(row, col, dinv, B1, B2, E);

    k_relu2<<<nbN4, 256, 0, stream>>>(b1, dinv, B2, B1, N * 4);
    k_scatter<<<nbE, 256, 0, stream>>>(row, col, dinv, B1, B2, E);

    k_final<<<nbN, 256, 0, stream>>>(B2, W2, b2, out, N);
}

// Round 2
// 650.391 us; speedup vs baseline: 8.4306x; 8.4306x over previous
//
#include <hip/hip_runtime.h>
#include <hip/hip_bf16.h>

#define F_IN  512
#define F_HID 16
#define F_OUT 40

typedef __attribute__((ext_vector_type(4))) float f32x4;
typedef __attribute__((ext_vector_type(8))) short s16x8;

// ---------------- CSR build: histogram -> scan -> fill ----------------

__global__ void k_zero(int* __restrict__ cnt, int n) {
    int i = blockIdx.x * 256 + threadIdx.x;
    if (i < n) cnt[i] = 0;
}

__global__ void k_hist(const int* __restrict__ col, int* __restrict__ cnt, int nE) {
    int e = blockIdx.x * 256 + threadIdx.x;
    if (e < nE) atomicAdd(&cnt[col[e]], 1);
}

__global__ void k_dinv(const int* __restrict__ cnt, float* __restrict__ dinv, int n) {
    int i = blockIdx.x * 256 + threadIdx.x;
    if (i < n) dinv[i] = rsqrtf((float)cnt[i] + 1.0f);   // +1 self-loop
}

// per-block sums of cnt
__global__ void k_bsum(const int* __restrict__ cnt, int* __restrict__ bsums, int n) {
    __shared__ int red[256];
    int i = blockIdx.x * 256 + threadIdx.x;
    red[threadIdx.x] = (i < n) ? cnt[i] : 0;
    __syncthreads();
    for (int off = 128; off; off >>= 1) {
        if (threadIdx.x < off) red[threadIdx.x] += red[threadIdx.x + off];
        __syncthreads();
    }
    if (threadIdx.x == 0) bsums[blockIdx.x] = red[0];
}

// single-block exclusive scan of block sums (nb <= 512)
__global__ void k_scan_bsums(int* __restrict__ bsums, int nb) {
    __shared__ int s[512];
    int t = threadIdx.x;
    s[t] = (t < nb) ? bsums[t] : 0;
    __syncthreads();
    for (int off = 1; off < 512; off <<= 1) {
        int v = (t >= off) ? s[t - off] : 0;
        __syncthreads();
        s[t] += v;
        __syncthreads();
    }
    if (t < nb) bsums[t] = (t == 0) ? 0 : s[t - 1];
}

// intra-block exclusive scan + block offset -> start[], cursor[]
__global__ void k_scan_final(const int* __restrict__ cnt, const int* __restrict__ bsums,
                             int* __restrict__ start, int* __restrict__ cursor,
                             int n, int nE) {
    __shared__ int s[256];
    int i = blockIdx.x * 256 + threadIdx.x;
    int v = (i < n) ? cnt[i] : 0;
    s[threadIdx.x] = v;
    __syncthreads();
    for (int off = 1; off < 256; off <<= 1) {
        int u = (threadIdx.x >= off) ? s[threadIdx.x - off] : 0;
        __syncthreads();
        s[threadIdx.x] += u;
        __syncthreads();
    }
    if (i < n) {
        int ex = s[threadIdx.x] - v + bsums[blockIdx.x];
        start[i] = ex;
        cursor[i] = ex;
    }
    if (i == 0) start[n] = nE;
}

__global__ void k_fill(const int* __restrict__ row, const int* __restrict__ col,
                       int* __restrict__ cursor, int* __restrict__ csr, int nE) {
    int e = blockIdx.x * 256 + threadIdx.x;
    if (e >= nE) return;
    int pos = atomicAdd(&cursor[col[e]], 1);
    csr[pos] = row[e];
}

// ---------------- g1 = dinv * (x @ W1)  (bf16 MFMA, W1 register-resident) ----------------
__global__ __launch_bounds__(256) void k_xw1(const float* __restrict__ x,
                                             const float* __restrict__ W1,
                                             const float* __restrict__ dinv,
                                             float* __restrict__ g1, int n_tiles) {
    int lane = threadIdx.x & 63;
    int wid  = threadIdx.x >> 6;
    int m = lane & 15;
    int g = lane >> 4;

    s16x8 bf[16];
#pragma unroll
    for (int kb = 0; kb < 16; ++kb) {
        union { s16x8 s; unsigned u[4]; } bu;
#pragma unroll
        for (int p = 0; p < 4; ++p) {
            int k0 = kb * 32 + g * 8 + p * 2;
            float lo = W1[(k0 + 0) * F_HID + m];
            float hi = W1[(k0 + 1) * F_HID + m];
            unsigned pk;
            asm("v_cvt_pk_bf16_f32 %0, %1, %2" : "=v"(pk) : "v"(lo), "v"(hi));
            bu.u[p] = pk;
        }
        bf[kb] = bu.s;
    }

    int tile = blockIdx.x * 4 + wid;
    if (tile >= n_tiles) return;

    const float* xr = x + (size_t)(tile * 16 + m) * F_IN + g * 8;
    f32x4 acc = {0.f, 0.f, 0.f, 0.f};
#pragma unroll
    for (int kb = 0; kb < 16; ++kb) {
        f32x4 xa = *(const f32x4*)(xr + kb * 32);
        f32x4 xb = *(const f32x4*)(xr + kb * 32 + 4);
        union { s16x8 s; unsigned u[4]; } au;
        asm("v_cvt_pk_bf16_f32 %0, %1, %2" : "=v"(au.u[0]) : "v"(xa.x), "v"(xa.y));
        asm("v_cvt_pk_bf16_f32 %0, %1, %2" : "=v"(au.u[1]) : "v"(xa.z), "v"(xa.w));
        asm("v_cvt_pk_bf16_f32 %0, %1, %2" : "=v"(au.u[2]) : "v"(xb.x), "v"(xb.y));
        asm("v_cvt_pk_bf16_f32 %0, %1, %2" : "=v"(au.u[3]) : "v"(xb.z), "v"(xb.w));
        acc = __builtin_amdgcn_mfma_f32_16x16x32_bf16(au.s, bf[kb], acc, 0, 0, 0);
    }
#pragma unroll
    for (int p = 0; p < 4; ++p) {
        int rr = tile * 16 + g * 4 + p;
        g1[(size_t)rr * F_HID + m] = acc[p] * dinv[rr];
    }
}

// ---------------- gather layer 1 (fused relu + layer-2 pre-scale) ----------------
// g2[n] = dinv[n] * relu( dinv[n]*(g1[n] + sum_{in} g1[r]) + b1 )
__global__ __launch_bounds__(256) void k_gather1(const int* __restrict__ start,
                                                 const int* __restrict__ csr,
                                                 const float* __restrict__ g1,
                                                 const float* __restrict__ dinv,
                                                 const float* __restrict__ b1,
                                                 float* __restrict__ g2, int n) {
    int wid = threadIdx.x >> 6, lane = threadIdx.x & 63;
    int node = blockIdx.x * 4 + wid;
    if (node >= n) return;
    int f = lane & 15, sub = lane >> 4;
    int s0 = start[node], s1 = start[node + 1];
    float acc = 0.f;
    for (int e = s0 + sub; e < s1; e += 4) {
        int r = csr[e];
        acc += g1[(size_t)r * F_HID + f];
    }
    acc += __shfl_xor(acc, 16);
    acc += __shfl_xor(acc, 32);
    float di = dinv[node];
    float self = g1[(size_t)node * F_HID + f];
    float h = fmaxf(di * (acc + self) + b1[f], 0.f);
    if (sub == 0) g2[(size_t)node * F_HID + f] = di * h;
}

// ---------------- gather layer 2: agg2[n] = dinv[n] * (g2[n] + sum_{in} g2[r]) ----------------
__global__ __launch_bounds__(256) void k_gather2(const int* __restrict__ start,
                                                 const int* __restrict__ csr,
                                                 const float* __restrict__ g2,
                                                 const float* __restrict__ dinv,
                                                 float* __restrict__ agg2, int n) {
    int wid = threadIdx.x >> 6, lane = threadIdx.x & 63;
    int node = blockIdx.x * 4 + wid;
    if (node >= n) return;
    int f = lane & 15, sub = lane >> 4;
    int s0 = start[node], s1 = start[node + 1];
    float acc = 0.f;
    for (int e = s0 + sub; e < s1; e += 4) {
        int r = csr[e];
        acc += g2[(size_t)r * F_HID + f];
    }
    acc += __shfl_xor(acc, 16);
    acc += __shfl_xor(acc, 32);
    float di = dinv[node];
    float self = g2[(size_t)node * F_HID + f];
    if (sub == 0) agg2[(size_t)node * F_HID + f] = di * (acc + self);
}

// ---------------- out = log_softmax(agg2 @ W2 + b2) ----------------
__global__ __launch_bounds__(256) void k_final(const float* __restrict__ agg2,
                                               const float* __restrict__ W2,
                                               const float* __restrict__ b2,
                                               float* __restrict__ out, int n) {
    __shared__ float W2s[F_HID * F_OUT];
    __shared__ float b2s[F_OUT];
    for (int i = threadIdx.x; i < F_HID * F_OUT; i += 256) W2s[i] = W2[i];
    if (threadIdx.x < F_OUT) b2s[threadIdx.x] = b2[threadIdx.x];
    __syncthreads();

    int nidx = blockIdx.x * 256 + threadIdx.x;
    if (nidx >= n) return;

    float a[F_HID];
    const f32x4* ap = (const f32x4*)(agg2 + (size_t)nidx * F_HID);
#pragma unroll
    for (int q = 0; q < 4; ++q) {
        f32x4 v = ap[q];
        a[q * 4 + 0] = v.x; a[q * 4 + 1] = v.y; a[q * 4 + 2] = v.z; a[q * 4 + 3] = v.w;
    }

    float o[F_OUT];
#pragma unroll
    for (int j = 0; j < F_OUT; ++j) {
        float acc = b2s[j];
#pragma unroll
        for (int k = 0; k < F_HID; ++k) acc += a[k] * W2s[k * F_OUT + j];
        o[j] = acc;
    }
    float mx = o[0];
#pragma unroll
    for (int j = 1; j < F_OUT; ++j) mx = fmaxf(mx, o[j]);
    float s = 0.f;
#pragma unroll
    for (int j = 0; j < F_OUT; ++j) s += __expf(o[j] - mx);
    float lse = mx + __logf(s);

    float* op = out + (size_t)nidx * F_OUT;
#pragma unroll
    for (int j = 0; j < F_OUT; ++j) op[j] = o[j] - lse;
}

// ---------------- launcher ----------------

extern "C" void kernel_launch(void* const* d_in, const int* in_sizes, int n_in,
                              void* d_out, int out_size, void* d_ws, size_t ws_size,
                              hipStream_t stream) {
    const float* x  = (const float*)d_in[0];
    const int*   ei = (const int*)d_in[1];
    const float* W1 = (const float*)d_in[2];
    const float* b1 = (const float*)d_in[3];
    const float* W2 = (const float*)d_in[4];
    const float* b2 = (const float*)d_in[5];
    float* out = (float*)d_out;

    const int N = out_size / F_OUT;       // 100000
    const int E = in_sizes[1] / 2;        // 3200000
    const int* row = ei;                  // sources
    const int* col = ei + E;              // targets

    // workspace layout (all 16B-aligned: every count divisible by 4)
    int* cnt    = (int*)d_ws;                 // N
    int* start  = cnt + N;                    // N+4 (N+1 used)
    int* cursor = start + N + 4;              // N
    int* bsums  = cursor + N;                 // 512
    int* csr    = bsums + 512;                // E
    float* dinv = (float*)(csr + E);          // N
    float* B1   = dinv + N;                   // N*16
    float* B2   = B1 + (size_t)N * F_HID;     // N*16

    int nbN  = (N + 255) / 256;   // 391
    int nbE  = (E + 255) / 256;   // 12500
    int tiles = (N + 15) / 16;    // 6250
    int nbT  = (tiles + 3) / 4;
    int nbG  = (N + 3) / 4;       // 4 nodes (waves) per block

    k_zero<<<nbN, 256, 0, stream>>>(cnt, N);
    k_hist<<<nbE, 256, 0, stream>>>(col, cnt, E);
    k_dinv<<<nbN, 256, 0, stream>>>(cnt, dinv, N);

    k_bsum<<<nbN, 256, 0, stream>>>(cnt, bsums, N);
    k_scan_bsums<<<1, 512, 0, stream>>>(bsums, nbN);
    k_scan_final<<<nbN, 256, 0, stream>>>(cnt, bsums, start, cursor, N, E);
    k_fill<<<nbE, 256, 0, stream>>>(row, col, cursor, csr, E);

    k_xw1<<<nbT, 256, 0, stream>>>(x, W1, dinv, B1, tiles);

    k_gather1<<<nbG, 256, 0, stream>>>(start, csr, B1, dinv, b1, B2, N);
    k_gather2<<<nbG, 256, 0, stream>>>(start, csr, B2, dinv, B1, N);

    k_final<<<nbN, 256, 0, stream>>>(B1, W2, b2, out, N);
}

// Round 3
// 344.964 us; speedup vs baseline: 15.8949x; 1.8854x over previous
//
#include <hip/hip_runtime.h>
#include <hip/hip_bf16.h>

#define F_IN  512
#define F_HID 16
#define F_OUT 40
#define CH    8192   // edges per workgroup in bucket pass

typedef __attribute__((ext_vector_type(4))) float f32x4;
typedef __attribute__((ext_vector_type(8))) short s16x8;

// ---------------- bucketed CSR build ----------------
// bucket = col >> 9  (512 nodes per bucket, NBUCK <= 256)

__global__ void k_zero_small(int* __restrict__ p, int n) {
    int i = threadIdx.x;
    if (i < n) p[i] = 0;
}

__global__ __launch_bounds__(256) void k_bhist(const int* __restrict__ col,
                                               int* __restrict__ bcnt, int nE) {
    __shared__ int bh[256];
    bh[threadIdx.x] = 0;
    __syncthreads();
    int base = blockIdx.x * CH;
    int end  = min(base + CH, nE);
    for (int e = base + threadIdx.x; e < end; e += 256)
        atomicAdd(&bh[col[e] >> 9], 1);
    __syncthreads();
    int v = bh[threadIdx.x];
    if (v) atomicAdd(&bcnt[threadIdx.x], v);
}

__global__ void k_bscan(const int* __restrict__ bcnt, int* __restrict__ bstart,
                        int* __restrict__ bcur, int nb, int nE) {
    __shared__ int s[256];
    int t = threadIdx.x;
    s[t] = (t < nb) ? bcnt[t] : 0;
    __syncthreads();
    for (int off = 1; off < 256; off <<= 1) {
        int v = (t >= off) ? s[t - off] : 0;
        __syncthreads();
        s[t] += v;
        __syncthreads();
    }
    int ex = (t == 0) ? 0 : s[t - 1];
    if (t < nb) { bstart[t] = ex; bcur[t] = ex; }
    if (t == nb) bstart[t] = nE;
}

// scatter packed (row<<9 | col_local) into bucket-contiguous regions
__global__ __launch_bounds__(256) void k_bscatter(const int* __restrict__ row,
                                                  const int* __restrict__ colv,
                                                  int* __restrict__ bcur,
                                                  int* __restrict__ pairs, int nE) {
    __shared__ int colS[CH];
    __shared__ int bh[256];
    __shared__ int lcur[256];
    bh[threadIdx.x] = 0;
    __syncthreads();
    int base = blockIdx.x * CH;
    int end  = min(base + CH, nE);
    for (int e = base + threadIdx.x; e < end; e += 256) {
        int c = colv[e];
        colS[e - base] = c;
        atomicAdd(&bh[c >> 9], 1);
    }
    __syncthreads();
    int v = bh[threadIdx.x];
    if (v) lcur[threadIdx.x] = atomicAdd(&bcur[threadIdx.x], v);
    __syncthreads();
    for (int e = base + threadIdx.x; e < end; e += 256) {
        int c = colS[e - base];
        int pos = atomicAdd(&lcur[c >> 9], 1);
        pairs[pos] = (row[e] << 9) | (c & 511);
    }
}

// per-bucket node histogram (LDS only) -> dense cnt + dinv
__global__ __launch_bounds__(256) void k_ncnt(const int* __restrict__ bstart,
                                              const int* __restrict__ pairs,
                                              int* __restrict__ cnt,
                                              float* __restrict__ dinv, int n) {
    __shared__ int h[512];
    h[threadIdx.x] = 0; h[threadIdx.x + 256] = 0;
    __syncthreads();
    int s0 = bstart[blockIdx.x], s1 = bstart[blockIdx.x + 1];
    for (int e = s0 + threadIdx.x; e < s1; e += 256)
        atomicAdd(&h[pairs[e] & 511], 1);
    __syncthreads();
    int nbase = blockIdx.x << 9;
#pragma unroll
    for (int q = 0; q < 2; ++q) {
        int node = nbase + threadIdx.x + q * 256;
        if (node < n) {
            int c = h[threadIdx.x + q * 256];
            cnt[node] = c;
            dinv[node] = rsqrtf((float)c + 1.0f);
        }
    }
}

// ---------------- global prefix over node counts ----------------

__global__ void k_bsum(const int* __restrict__ cnt, int* __restrict__ bsums, int n) {
    __shared__ int red[256];
    int i = blockIdx.x * 256 + threadIdx.x;
    red[threadIdx.x] = (i < n) ? cnt[i] : 0;
    __syncthreads();
    for (int off = 128; off; off >>= 1) {
        if (threadIdx.x < off) red[threadIdx.x] += red[threadIdx.x + off];
        __syncthreads();
    }
    if (threadIdx.x == 0) bsums[blockIdx.x] = red[0];
}

__global__ void k_scan_bsums(int* __restrict__ bsums, int nb) {
    __shared__ int s[512];
    int t = threadIdx.x;
    s[t] = (t < nb) ? bsums[t] : 0;
    __syncthreads();
    for (int off = 1; off < 512; off <<= 1) {
        int v = (t >= off) ? s[t - off] : 0;
        __syncthreads();
        s[t] += v;
        __syncthreads();
    }
    if (t < nb) bsums[t] = (t == 0) ? 0 : s[t - 1];
}

__global__ void k_scan_final(const int* __restrict__ cnt, const int* __restrict__ bsums,
                             int* __restrict__ start, int n, int nE) {
    __shared__ int s[256];
    int i = blockIdx.x * 256 + threadIdx.x;
    int v = (i < n) ? cnt[i] : 0;
    s[threadIdx.x] = v;
    __syncthreads();
    for (int off = 1; off < 256; off <<= 1) {
        int u = (threadIdx.x >= off) ? s[threadIdx.x - off] : 0;
        __syncthreads();
        s[threadIdx.x] += u;
        __syncthreads();
    }
    if (i < n) start[i] = s[threadIdx.x] - v + bsums[blockIdx.x];
    if (i == 0) start[n] = nE;
}

// per-bucket fine scatter with LDS cursors; csr writes land in a ~64KB window
__global__ __launch_bounds__(256) void k_fill2(const int* __restrict__ bstart,
                                               const int* __restrict__ pairs,
                                               const int* __restrict__ start,
                                               int* __restrict__ csr, int n) {
    __shared__ int cur[512];
    int nbase = blockIdx.x << 9;
#pragma unroll
    for (int q = 0; q < 2; ++q) {
        int node = nbase + threadIdx.x + q * 256;
        cur[threadIdx.x + q * 256] = (node < n) ? start[node] : 0;
    }
    __syncthreads();
    int s0 = bstart[blockIdx.x], s1 = bstart[blockIdx.x + 1];
    for (int e = s0 + threadIdx.x; e < s1; e += 256) {
        int v = pairs[e];
        int pos = atomicAdd(&cur[v & 511], 1);
        csr[pos] = v >> 9;
    }
}

// ---------------- g1 = dinv * (x @ W1)  (bf16 MFMA, W1 register-resident) ----------------
__global__ __launch_bounds__(256) void k_xw1(const float* __restrict__ x,
                                             const float* __restrict__ W1,
                                             const float* __restrict__ dinv,
                                             float* __restrict__ g1, int n_tiles) {
    int lane = threadIdx.x & 63;
    int wid  = threadIdx.x >> 6;
    int m = lane & 15;
    int g = lane >> 4;

    s16x8 bf[16];
#pragma unroll
    for (int kb = 0; kb < 16; ++kb) {
        union { s16x8 s; unsigned u[4]; } bu;
#pragma unroll
        for (int p = 0; p < 4; ++p) {
            int k0 = kb * 32 + g * 8 + p * 2;
            float lo = W1[(k0 + 0) * F_HID + m];
            float hi = W1[(k0 + 1) * F_HID + m];
            unsigned pk;
            asm("v_cvt_pk_bf16_f32 %0, %1, %2" : "=v"(pk) : "v"(lo), "v"(hi));
            bu.u[p] = pk;
        }
        bf[kb] = bu.s;
    }

    int tile = blockIdx.x * 4 + wid;
    if (tile >= n_tiles) return;

    const float* xr = x + (size_t)(tile * 16 + m) * F_IN + g * 8;
    f32x4 acc = {0.f, 0.f, 0.f, 0.f};
#pragma unroll
    for (int kb = 0; kb < 16; ++kb) {
        f32x4 xa = *(const f32x4*)(xr + kb * 32);
        f32x4 xb = *(const f32x4*)(xr + kb * 32 + 4);
        union { s16x8 s; unsigned u[4]; } au;
        asm("v_cvt_pk_bf16_f32 %0, %1, %2" : "=v"(au.u[0]) : "v"(xa.x), "v"(xa.y));
        asm("v_cvt_pk_bf16_f32 %0, %1, %2" : "=v"(au.u[1]) : "v"(xa.z), "v"(xa.w));
        asm("v_cvt_pk_bf16_f32 %0, %1, %2" : "=v"(au.u[2]) : "v"(xb.x), "v"(xb.y));
        asm("v_cvt_pk_bf16_f32 %0, %1, %2" : "=v"(au.u[3]) : "v"(xb.z), "v"(xb.w));
        acc = __builtin_amdgcn_mfma_f32_16x16x32_bf16(au.s, bf[kb], acc, 0, 0, 0);
    }
#pragma unroll
    for (int p = 0; p < 4; ++p) {
        int rr = tile * 16 + g * 4 + p;
        g1[(size_t)rr * F_HID + m] = acc[p] * dinv[rr];
    }
}

// ---------------- gather layer 1 (fused relu + layer-2 pre-scale) ----------------
__global__ __launch_bounds__(256) void k_gather1(const int* __restrict__ start,
                                                 const int* __restrict__ csr,
                                                 const float* __restrict__ g1,
                                                 const float* __restrict__ dinv,
                                                 const float* __restrict__ b1,
                                                 float* __restrict__ g2, int n) {
    int wid = threadIdx.x >> 6, lane = threadIdx.x & 63;
    int node = blockIdx.x * 4 + wid;
    if (node >= n) return;
    int f = lane & 15, sub = lane >> 4;
    int s0 = start[node], s1 = start[node + 1];
    float acc = 0.f;
    for (int e = s0 + sub; e < s1; e += 4) {
        int r = csr[e];
        acc += g1[(size_t)r * F_HID + f];
    }
    acc += __shfl_xor(acc, 16);
    acc += __shfl_xor(acc, 32);
    float di = dinv[node];
    float self = g1[(size_t)node * F_HID + f];
    float h = fmaxf(di * (acc + self) + b1[f], 0.f);
    if (sub == 0) g2[(size_t)node * F_HID + f] = di * h;
}

// ---------------- gather layer 2 ----------------
__global__ __launch_bounds__(256) void k_gather2(const int* __restrict__ start,
                                                 const int* __restrict__ csr,
                                                 const float* __restrict__ g2,
                                                 const float* __restrict__ dinv,
                                                 float* __restrict__ agg2, int n) {
    int wid = threadIdx.x >> 6, lane = threadIdx.x & 63;
    int node = blockIdx.x * 4 + wid;
    if (node >= n) return;
    int f = lane & 15, sub = lane >> 4;
    int s0 = start[node], s1 = start[node + 1];
    float acc = 0.f;
    for (int e = s0 + sub; e < s1; e += 4) {
        int r = csr[e];
        acc += g2[(size_t)r * F_HID + f];
    }
    acc += __shfl_xor(acc, 16);
    acc += __shfl_xor(acc, 32);
    float di = dinv[node];
    float self = g2[(size_t)node * F_HID + f];
    if (sub == 0) agg2[(size_t)node * F_HID + f] = di * (acc + self);
}

// ---------------- out = log_softmax(agg2 @ W2 + b2) ----------------
__global__ __launch_bounds__(256) void k_final(const float* __restrict__ agg2,
                                               const float* __restrict__ W2,
                                               const float* __restrict__ b2,
                                               float* __restrict__ out, int n) {
    __shared__ float W2s[F_HID * F_OUT];
    __shared__ float b2s[F_OUT];
    for (int i = threadIdx.x; i < F_HID * F_OUT; i += 256) W2s[i] = W2[i];
    if (threadIdx.x < F_OUT) b2s[threadIdx.x] = b2[threadIdx.x];
    __syncthreads();

    int nidx = blockIdx.x * 256 + threadIdx.x;
    if (nidx >= n) return;

    float a[F_HID];
    const f32x4* ap = (const f32x4*)(agg2 + (size_t)nidx * F_HID);
#pragma unroll
    for (int q = 0; q < 4; ++q) {
        f32x4 v = ap[q];
        a[q * 4 + 0] = v.x; a[q * 4 + 1] = v.y; a[q * 4 + 2] = v.z; a[q * 4 + 3] = v.w;
    }

    float o[F_OUT];
#pragma unroll
    for (int j = 0; j < F_OUT; ++j) {
        float acc = b2s[j];
#pragma unroll
        for (int k = 0; k < F_HID; ++k) acc += a[k] * W2s[k * F_OUT + j];
        o[j] = acc;
    }
    float mx = o[0];
#pragma unroll
    for (int j = 1; j < F_OUT; ++j) mx = fmaxf(mx, o[j]);
    float s = 0.f;
#pragma unroll
    for (int j = 0; j < F_OUT; ++j) s += __expf(o[j] - mx);
    float lse = mx + __logf(s);

    float* op = out + (size_t)nidx * F_OUT;
#pragma unroll
    for (int j = 0; j < F_OUT; ++j) op[j] = o[j] - lse;
}

// ---------------- launcher ----------------

extern "C" void kernel_launch(void* const* d_in, const int* in_sizes, int n_in,
                              void* d_out, int out_size, void* d_ws, size_t ws_size,
                              hipStream_t stream) {
    const float* x  = (const float*)d_in[0];
    const int*   ei = (const int*)d_in[1];
    const float* W1 = (const float*)d_in[2];
    const float* b1 = (const float*)d_in[3];
    const float* W2 = (const float*)d_in[4];
    const float* b2 = (const float*)d_in[5];
    float* out = (float*)d_out;

    const int N = out_size / F_OUT;       // 100000
    const int E = in_sizes[1] / 2;        // 3200000
    const int* row = ei;                  // sources
    const int* col = ei + E;              // targets

    const int NBUCK = (N + 511) >> 9;     // 196
    const int NWGE  = (E + CH - 1) / CH;  // 391
    const int nbN   = (N + 255) / 256;    // 391
    const int tiles = (N + 15) / 16;
    const int nbT   = (tiles + 3) / 4;
    const int nbG   = (N + 3) / 4;

    // workspace layout (ints unless noted); pairs aliases B1+B2 (dead once csr built)
    int* bcnt   = (int*)d_ws;                 // 256
    int* bstart = bcnt + 256;                 // 256 (NBUCK+1 used)
    int* bcur   = bstart + 256;               // 256
    int* cnt    = bcur + 256;                 // N
    int* start  = cnt + N;                    // N+4
    int* bsums  = start + N + 4;              // 512
    int* csr    = bsums + 512;                // E
    float* dinv = (float*)(csr + E);          // N
    float* B1   = dinv + N;                   // 16N
    float* B2   = B1 + (size_t)N * F_HID;     // 16N
    int* pairs  = (int*)B1;                   // E (= 32N) aliases B1,B2

    k_zero_small<<<1, 256, 0, stream>>>(bcnt, 256);
    k_bhist<<<NWGE, 256, 0, stream>>>(col, bcnt, E);
    k_bscan<<<1, 256, 0, stream>>>(bcnt, bstart, bcur, NBUCK, E);
    k_bscatter<<<NWGE, 256, 0, stream>>>(row, col, bcur, pairs, E);
    k_ncnt<<<NBUCK, 256, 0, stream>>>(bstart, pairs, cnt, dinv, N);

    k_bsum<<<nbN, 256, 0, stream>>>(cnt, bsums, N);
    k_scan_bsums<<<1, 512, 0, stream>>>(bsums, nbN);
    k_scan_final<<<nbN, 256, 0, stream>>>(cnt, bsums, start, N, E);
    k_fill2<<<NBUCK, 256, 0, stream>>>(bstart, pairs, start, csr, N);

    k_xw1<<<nbT, 256, 0, stream>>>(x, W1, dinv, B1, tiles);

    k_gather1<<<nbG, 256, 0, stream>>>(start, csr, B1, dinv, b1, B2, N);
    k_gather2<<<nbG, 256, 0, stream>>>(start, csr, B2, dinv, B1, N);

    k_final<<<nbN, 256, 0, stream>>>(B1, W2, b2, out, N);
}

// Round 4
// 260.120 us; speedup vs baseline: 21.0794x; 1.3262x over previous
//
#include <hip/hip_runtime.h>
#include <hip/hip_bf16.h>

#define F_IN  512
#define F_HID 16
#define F_OUT 40
#define CH    8192   // edges per workgroup in bucket pass

typedef __attribute__((ext_vector_type(4))) float f32x4;
typedef __attribute__((ext_vector_type(8))) short s16x8;
typedef unsigned short ushort_t;

__device__ __forceinline__ float bf2f(ushort_t u) {
    union { unsigned u; float f; } v; v.u = (unsigned)u << 16; return v.f;
}
__device__ __forceinline__ ushort_t f2bf(float f) {
    __hip_bfloat16 h = __float2bfloat16(f);   // RNE
    union { __hip_bfloat16 h; ushort_t u; } v; v.h = h; return v.u;
}

// ---------------- bucketed CSR build ----------------
// bucket = col >> 9  (512 nodes per bucket, NBUCK <= 256)

__global__ void k_zero_small(int* __restrict__ p, int n) {
    int i = threadIdx.x;
    if (i < n) p[i] = 0;
}

__global__ __launch_bounds__(256) void k_bhist(const int* __restrict__ col,
                                               int* __restrict__ bcnt, int nE) {
    __shared__ int bh[256];
    bh[threadIdx.x] = 0;
    __syncthreads();
    int base = blockIdx.x * CH;
    int end  = min(base + CH, nE);
    for (int e = base + threadIdx.x; e < end; e += 256)
        atomicAdd(&bh[col[e] >> 9], 1);
    __syncthreads();
    int v = bh[threadIdx.x];
    if (v) atomicAdd(&bcnt[threadIdx.x], v);
}

__global__ void k_bscan(const int* __restrict__ bcnt, int* __restrict__ bstart,
                        int* __restrict__ bcur, int nb, int nE) {
    __shared__ int s[256];
    int t = threadIdx.x;
    s[t] = (t < nb) ? bcnt[t] : 0;
    __syncthreads();
    for (int off = 1; off < 256; off <<= 1) {
        int v = (t >= off) ? s[t - off] : 0;
        __syncthreads();
        s[t] += v;
        __syncthreads();
    }
    int ex = (t == 0) ? 0 : s[t - 1];
    if (t < nb) { bstart[t] = ex; bcur[t] = ex; }
    if (t == nb) bstart[t] = nE;
}

// scatter packed (row<<9 | col_local) into bucket-contiguous regions
__global__ __launch_bounds__(256) void k_bscatter(const int* __restrict__ row,
                                                  const int* __restrict__ colv,
                                                  int* __restrict__ bcur,
                                                  int* __restrict__ pairs, int nE) {
    __shared__ int colS[CH];
    __shared__ int bh[256];
    __shared__ int lcur[256];
    bh[threadIdx.x] = 0;
    __syncthreads();
    int base = blockIdx.x * CH;
    int end  = min(base + CH, nE);
    for (int e = base + threadIdx.x; e < end; e += 256) {
        int c = colv[e];
        colS[e - base] = c;
        atomicAdd(&bh[c >> 9], 1);
    }
    __syncthreads();
    int v = bh[threadIdx.x];
    if (v) lcur[threadIdx.x] = atomicAdd(&bcur[threadIdx.x], v);
    __syncthreads();
    for (int e = base + threadIdx.x; e < end; e += 256) {
        int c = colS[e - base];
        int pos = atomicAdd(&lcur[c >> 9], 1);
        pairs[pos] = (row[e] << 9) | (c & 511);
    }
}

// one kernel per bucket: LDS node-histogram -> LDS scan (bstart[b] is the
// global prefix already) -> start/dinv writes -> LDS-cursor fine scatter.
__global__ __launch_bounds__(256) void k_build(const int* __restrict__ bstart,
                                               const int* __restrict__ pairs,
                                               int* __restrict__ start,
                                               int* __restrict__ csr,
                                               float* __restrict__ dinv,
                                               int n, int nE, int nbuck) {
    __shared__ int h[512];
    __shared__ int s[256];
    __shared__ int cur[512];
    int t = threadIdx.x;
    h[t] = 0; h[t + 256] = 0;
    __syncthreads();
    int s0 = bstart[blockIdx.x], s1 = bstart[blockIdx.x + 1];
    for (int e = s0 + t; e < s1; e += 256)
        atomicAdd(&h[pairs[e] & 511], 1);
    __syncthreads();
    int c0 = h[2 * t], c1 = h[2 * t + 1];
    int tsum = c0 + c1;
    s[t] = tsum;
    __syncthreads();
    for (int off = 1; off < 256; off <<= 1) {
        int v = (t >= off) ? s[t - off] : 0;
        __syncthreads();
        s[t] += v;
        __syncthreads();
    }
    int ex = s[t] - tsum;          // exclusive within bucket
    int st0 = s0 + ex, st1 = st0 + c0;
    int nbase = blockIdx.x << 9;
    int n0 = nbase + 2 * t, n1 = n0 + 1;
    if (n0 < n) { start[n0] = st0; dinv[n0] = rsqrtf((float)c0 + 1.0f); }
    if (n1 < n) { start[n1] = st1; dinv[n1] = rsqrtf((float)c1 + 1.0f); }
    cur[2 * t] = st0; cur[2 * t + 1] = st1;
    if (blockIdx.x == nbuck - 1 && t == 0) start[n] = nE;
    __syncthreads();
    for (int e = s0 + t; e < s1; e += 256) {
        int v = pairs[e];
        int pos = atomicAdd(&cur[v & 511], 1);
        csr[pos] = v >> 9;
    }
}

// ---------------- g1 = bf16( dinv * (x @ W1) )  (bf16 MFMA, W1 register-resident) ----------------
__global__ __launch_bounds__(256) void k_xw1(const float* __restrict__ x,
                                             const float* __restrict__ W1,
                                             const float* __restrict__ dinv,
                                             ushort_t* __restrict__ g1b, int n_tiles) {
    int lane = threadIdx.x & 63;
    int wid  = threadIdx.x >> 6;
    int m = lane & 15;
    int g = lane >> 4;

    s16x8 bf[16];
#pragma unroll
    for (int kb = 0; kb < 16; ++kb) {
        union { s16x8 s; unsigned u[4]; } bu;
#pragma unroll
        for (int p = 0; p < 4; ++p) {
            int k0 = kb * 32 + g * 8 + p * 2;
            float lo = W1[(k0 + 0) * F_HID + m];
            float hi = W1[(k0 + 1) * F_HID + m];
            unsigned pk;
            asm("v_cvt_pk_bf16_f32 %0, %1, %2" : "=v"(pk) : "v"(lo), "v"(hi));
            bu.u[p] = pk;
        }
        bf[kb] = bu.s;
    }

    int tile = blockIdx.x * 4 + wid;
    if (tile >= n_tiles) return;

    const float* xr = x + (size_t)(tile * 16 + m) * F_IN + g * 8;
    f32x4 acc = {0.f, 0.f, 0.f, 0.f};
#pragma unroll
    for (int kb = 0; kb < 16; ++kb) {
        f32x4 xa = *(const f32x4*)(xr + kb * 32);
        f32x4 xb = *(const f32x4*)(xr + kb * 32 + 4);
        union { s16x8 s; unsigned u[4]; } au;
        asm("v_cvt_pk_bf16_f32 %0, %1, %2" : "=v"(au.u[0]) : "v"(xa.x), "v"(xa.y));
        asm("v_cvt_pk_bf16_f32 %0, %1, %2" : "=v"(au.u[1]) : "v"(xa.z), "v"(xa.w));
        asm("v_cvt_pk_bf16_f32 %0, %1, %2" : "=v"(au.u[2]) : "v"(xb.x), "v"(xb.y));
        asm("v_cvt_pk_bf16_f32 %0, %1, %2" : "=v"(au.u[3]) : "v"(xb.z), "v"(xb.w));
        acc = __builtin_amdgcn_mfma_f32_16x16x32_bf16(au.s, bf[kb], acc, 0, 0, 0);
    }
#pragma unroll
    for (int p = 0; p < 4; ++p) {
        int rr = tile * 16 + g * 4 + p;
        g1b[(size_t)rr * F_HID + m] = f2bf(acc[p] * dinv[rr]);
    }
}

// ---------------- gather layer 1: g2 = bf16( dinv * relu( dinv*(g1[self]+sum g1[in]) + b1 ) ) ----------------
__global__ __launch_bounds__(256) void k_gather1(const int* __restrict__ start,
                                                 const int* __restrict__ csr,
                                                 const ushort_t* __restrict__ g1b,
                                                 const float* __restrict__ dinv,
                                                 const float* __restrict__ b1,
                                                 ushort_t* __restrict__ g2b, int n) {
    int wid = threadIdx.x >> 6, lane = threadIdx.x & 63;
    int node = blockIdx.x * 4 + wid;
    if (node >= n) return;
    int f = lane & 15, sub = lane >> 4;
    int s0 = start[node], s1 = start[node + 1];
    int len = s1 - s0;
    int q = (len + 3) >> 2;
    int beg = s0 + sub * q;
    int end = min(beg + q, s1);
    float a0 = 0.f, a1 = 0.f, a2 = 0.f, a3 = 0.f;
    int e = beg;
    for (; e + 4 <= end; e += 4) {
        int r0 = csr[e], r1 = csr[e + 1], r2 = csr[e + 2], r3 = csr[e + 3];
        a0 += bf2f(g1b[r0 * F_HID + f]);
        a1 += bf2f(g1b[r1 * F_HID + f]);
        a2 += bf2f(g1b[r2 * F_HID + f]);
        a3 += bf2f(g1b[r3 * F_HID + f]);
    }
    for (; e < end; ++e) a0 += bf2f(g1b[csr[e] * F_HID + f]);
    float acc = (a0 + a1) + (a2 + a3);
    acc += __shfl_xor(acc, 16);
    acc += __shfl_xor(acc, 32);
    acc += bf2f(g1b[(size_t)node * F_HID + f]);   // self-loop
    float di = dinv[node];
    float h = fmaxf(di * acc + b1[f], 0.f);
    if (sub == 0) g2b[(size_t)node * F_HID + f] = f2bf(di * h);
}

// ---------------- gather layer 2 fused with W2 + bias + log_softmax ----------------
__global__ __launch_bounds__(256) void k_gather2f(const int* __restrict__ start,
                                                  const int* __restrict__ csr,
                                                  const ushort_t* __restrict__ g2b,
                                                  const float* __restrict__ dinv,
                                                  const float* __restrict__ W2,
                                                  const float* __restrict__ b2,
                                                  float* __restrict__ out, int n) {
    int wid = threadIdx.x >> 6, lane = threadIdx.x & 63;
    int node = blockIdx.x * 4 + wid;
    if (node >= n) return;
    int f = lane & 15, sub = lane >> 4;
    int j = (lane < F_OUT) ? lane : 0;

    float w2c[F_HID];
#pragma unroll
    for (int k = 0; k < F_HID; ++k) w2c[k] = W2[k * F_OUT + j];
    float bj = b2[j];

    int s0 = start[node], s1 = start[node + 1];
    int len = s1 - s0;
    int q = (len + 3) >> 2;
    int beg = s0 + sub * q;
    int end = min(beg + q, s1);
    float a0 = 0.f, a1 = 0.f, a2 = 0.f, a3 = 0.f;
    int e = beg;
    for (; e + 4 <= end; e += 4) {
        int r0 = csr[e], r1 = csr[e + 1], r2 = csr[e + 2], r3 = csr[e + 3];
        a0 += bf2f(g2b[r0 * F_HID + f]);
        a1 += bf2f(g2b[r1 * F_HID + f]);
        a2 += bf2f(g2b[r2 * F_HID + f]);
        a3 += bf2f(g2b[r3 * F_HID + f]);
    }
    for (; e < end; ++e) a0 += bf2f(g2b[csr[e] * F_HID + f]);
    float acc = (a0 + a1) + (a2 + a3);
    acc += __shfl_xor(acc, 16);
    acc += __shfl_xor(acc, 32);
    acc += bf2f(g2b[(size_t)node * F_HID + f]);   // self-loop
    float a = dinv[node] * acc;                   // lane l holds a[l&15]

    float o = bj;
#pragma unroll
    for (int k = 0; k < F_HID; ++k) o += __shfl(a, k) * w2c[k];

    float mo = (lane < F_OUT) ? o : -3.4e38f;
#pragma unroll
    for (int off = 32; off; off >>= 1) mo = fmaxf(mo, __shfl_xor(mo, off));
    float ev = (lane < F_OUT) ? __expf(o - mo) : 0.f;
    float sv = ev;
#pragma unroll
    for (int off = 32; off; off >>= 1) sv += __shfl_xor(sv, off);
    float lse = mo + __logf(sv);
    if (lane < F_OUT) out[(size_t)node * F_OUT + lane] = o - lse;
}

// ---------------- launcher ----------------

extern "C" void kernel_launch(void* const* d_in, const int* in_sizes, int n_in,
                              void* d_out, int out_size, void* d_ws, size_t ws_size,
                              hipStream_t stream) {
    const float* x  = (const float*)d_in[0];
    const int*   ei = (const int*)d_in[1];
    const float* W1 = (const float*)d_in[2];
    const float* b1 = (const float*)d_in[3];
    const float* W2 = (const float*)d_in[4];
    const float* b2 = (const float*)d_in[5];
    float* out = (float*)d_out;

    const int N = out_size / F_OUT;       // 100000
    const int E = in_sizes[1] / 2;        // 3200000
    const int* row = ei;                  // sources
    const int* col = ei + E;              // targets

    const int NBUCK = (N + 511) >> 9;     // 196
    const int NWGE  = (E + CH - 1) / CH;  // 391
    const int tiles = (N + 15) / 16;
    const int nbT   = (tiles + 3) / 4;
    const int nbG   = (N + 3) / 4;

    // workspace layout
    int* bcnt     = (int*)d_ws;                 // 256
    int* bstart   = bcnt + 256;                 // 260 (NBUCK+1 used)
    int* bcur     = bstart + 260;               // 256
    int* start    = bcur + 256;                 // N+4
    int* csr      = start + N + 4;              // E
    int* pairs    = csr + E;                    // E
    float* dinv   = (float*)(pairs + E);        // N
    ushort_t* g1b = (ushort_t*)(dinv + N);      // 16N bf16
    ushort_t* g2b = g1b + (size_t)N * F_HID;    // 16N bf16

    k_zero_small<<<1, 256, 0, stream>>>(bcnt, 256);
    k_bhist<<<NWGE, 256, 0, stream>>>(col, bcnt, E);
    k_bscan<<<1, 256, 0, stream>>>(bcnt, bstart, bcur, NBUCK, E);
    k_bscatter<<<NWGE, 256, 0, stream>>>(row, col, bcur, pairs, E);
    k_build<<<NBUCK, 256, 0, stream>>>(bstart, pairs, start, csr, dinv, N, E, NBUCK);

    k_xw1<<<nbT, 256, 0, stream>>>(x, W1, dinv, g1b, tiles);

    k_gather1<<<nbG, 256, 0, stream>>>(start, csr, g1b, dinv, b1, g2b, N);
    k_gather2f<<<nbG, 256, 0, stream>>>(start, csr, g2b, dinv, W2, b2, out, N);
}

// Round 5
// 257.585 us; speedup vs baseline: 21.2868x; 1.0098x over previous
//
#include <hip/hip_runtime.h>
#include <hip/hip_bf16.h>

#define F_IN  512
#define F_HID 16
#define F_OUT 40
#define CH    8192   // edges per workgroup in bucket pass

typedef __attribute__((ext_vector_type(4))) float f32x4;
typedef __attribute__((ext_vector_type(8))) short s16x8;
typedef unsigned short ushort_t;
typedef unsigned int uint_t;

__device__ __forceinline__ float lof(uint_t v) { return __uint_as_float(v << 16); }
__device__ __forceinline__ float hif(uint_t v) { return __uint_as_float(v & 0xffff0000u); }
__device__ __forceinline__ ushort_t f2bf(float f) {
    __hip_bfloat16 h = __float2bfloat16(f);   // RNE
    union { __hip_bfloat16 h; ushort_t u; } v; v.h = h; return v.u;
}

// ---------------- bucketed CSR build ----------------
// bucket = col >> 9  (512 nodes per bucket, NBUCK <= 256 assumed: N <= 131072)

// per-block bucket histograms (no global atomics, no zeroing pass)
__global__ __launch_bounds__(1024) void k_bhist(const int* __restrict__ col,
                                                int* __restrict__ bhall, int nE) {
    __shared__ int bh[256];
    int t = threadIdx.x;
    if (t < 256) bh[t] = 0;
    __syncthreads();
    int base = blockIdx.x * CH;
    int end  = min(base + CH, nE);
    for (int e = base + t; e < end; e += 1024)
        atomicAdd(&bh[col[e] >> 9], 1);
    __syncthreads();
    if (t < 256) bhall[blockIdx.x * 256 + t] = bh[t];
}

// column-sum the per-block histograms (coalesced) then exclusive-scan
__global__ void k_bscan2(const int* __restrict__ bhall, int* __restrict__ bstart,
                         int* __restrict__ bcur, int nwge) {
    __shared__ int s[256];
    int t = threadIdx.x;
    int sum = 0;
    for (int w = 0; w < nwge; ++w) sum += bhall[w * 256 + t];
    s[t] = sum;
    __syncthreads();
    for (int off = 1; off < 256; off <<= 1) {
        int v = (t >= off) ? s[t - off] : 0;
        __syncthreads();
        s[t] += v;
        __syncthreads();
    }
    int ex = s[t] - sum;    // exclusive prefix; for t >= nbuck this equals E
    bstart[t] = ex;
    bcur[t] = ex;
    if (t == 255) bstart[256] = s[255];   // = E (buckets >= nbuck are empty)
}

// scatter packed (row<<9 | col_local) into bucket-contiguous regions
__global__ __launch_bounds__(1024) void k_bscatter(const int* __restrict__ row,
                                                   const int* __restrict__ colv,
                                                   int* __restrict__ bcur,
                                                   int* __restrict__ pairs, int nE) {
    __shared__ int colS[CH];
    __shared__ int bh[256];
    __shared__ int lcur[256];
    int t = threadIdx.x;
    if (t < 256) bh[t] = 0;
    __syncthreads();
    int base = blockIdx.x * CH;
    int end  = min(base + CH, nE);
    for (int e = base + t; e < end; e += 1024) {
        int c = colv[e];
        colS[e - base] = c;
        atomicAdd(&bh[c >> 9], 1);
    }
    __syncthreads();
    if (t < 256) {
        int v = bh[t];
        if (v) lcur[t] = atomicAdd(&bcur[t], v);
    }
    __syncthreads();
    for (int e = base + t; e < end; e += 1024) {
        int c = colS[e - base];
        int pos = atomicAdd(&lcur[c >> 9], 1);
        pairs[pos] = (row[e] << 9) | (c & 511);
    }
}

// one block per bucket: LDS node-histogram -> LDS scan (bstart[b] is the
// global prefix already) -> start/dinv writes -> LDS-cursor fine scatter.
__global__ __launch_bounds__(1024) void k_build(const int* __restrict__ bstart,
                                                const int* __restrict__ pairs,
                                                int* __restrict__ start,
                                                int* __restrict__ csr,
                                                float* __restrict__ dinv,
                                                int n, int nE) {
    __shared__ int h[512];
    __shared__ int s[512];
    __shared__ int cur[512];
    int t = threadIdx.x;
    if (t < 512) h[t] = 0;
    __syncthreads();
    int s0 = bstart[blockIdx.x], s1 = bstart[blockIdx.x + 1];
    for (int e = s0 + t; e < s1; e += 1024)
        atomicAdd(&h[pairs[e] & 511], 1);
    __syncthreads();
    if (t < 512) s[t] = h[t];
    __syncthreads();
    for (int off = 1; off < 512; off <<= 1) {
        int v = 0;
        if (t < 512 && t >= off) v = s[t - off];
        __syncthreads();
        if (t < 512) s[t] += v;
        __syncthreads();
    }
    if (t < 512) {
        int c = h[t];
        int st = s0 + s[t] - c;   // exclusive within bucket + bucket base
        int node = (blockIdx.x << 9) + t;
        if (node < n) {
            start[node] = st;
            dinv[node] = rsqrtf((float)c + 1.0f);
        }
        cur[t] = st;
    }
    if (blockIdx.x == 0 && t == 0) start[n] = nE;
    __syncthreads();
    for (int e = s0 + t; e < s1; e += 1024) {
        int v = pairs[e];
        int pos = atomicAdd(&cur[v & 511], 1);
        csr[pos] = v >> 9;
    }
}

// ---------------- g1 = bf16( dinv * (x @ W1) )  (bf16 MFMA, W1 register-resident) ----------------
__global__ __launch_bounds__(256) void k_xw1(const float* __restrict__ x,
                                             const float* __restrict__ W1,
                                             const float* __restrict__ dinv,
                                             ushort_t* __restrict__ g1b, int n_tiles) {
    int lane = threadIdx.x & 63;
    int wid  = threadIdx.x >> 6;
    int m = lane & 15;
    int g = lane >> 4;

    s16x8 bf[16];
#pragma unroll
    for (int kb = 0; kb < 16; ++kb) {
        union { s16x8 s; unsigned u[4]; } bu;
#pragma unroll
        for (int p = 0; p < 4; ++p) {
            int k0 = kb * 32 + g * 8 + p * 2;
            float lo = W1[(k0 + 0) * F_HID + m];
            float hi = W1[(k0 + 1) * F_HID + m];
            unsigned pk;
            asm("v_cvt_pk_bf16_f32 %0, %1, %2" : "=v"(pk) : "v"(lo), "v"(hi));
            bu.u[p] = pk;
        }
        bf[kb] = bu.s;
    }

    int tile = blockIdx.x * 4 + wid;
    if (tile >= n_tiles) return;

    const float* xr = x + (size_t)(tile * 16 + m) * F_IN + g * 8;
    f32x4 acc = {0.f, 0.f, 0.f, 0.f};
#pragma unroll
    for (int kb = 0; kb < 16; ++kb) {
        f32x4 xa = *(const f32x4*)(xr + kb * 32);
        f32x4 xb = *(const f32x4*)(xr + kb * 32 + 4);
        union { s16x8 s; unsigned u[4]; } au;
        asm("v_cvt_pk_bf16_f32 %0, %1, %2" : "=v"(au.u[0]) : "v"(xa.x), "v"(xa.y));
        asm("v_cvt_pk_bf16_f32 %0, %1, %2" : "=v"(au.u[1]) : "v"(xa.z), "v"(xa.w));
        asm("v_cvt_pk_bf16_f32 %0, %1, %2" : "=v"(au.u[2]) : "v"(xb.x), "v"(xb.y));
        asm("v_cvt_pk_bf16_f32 %0, %1, %2" : "=v"(au.u[3]) : "v"(xb.z), "v"(xb.w));
        acc = __builtin_amdgcn_mfma_f32_16x16x32_bf16(au.s, bf[kb], acc, 0, 0, 0);
    }
#pragma unroll
    for (int p = 0; p < 4; ++p) {
        int rr = tile * 16 + g * 4 + p;
        g1b[(size_t)rr * F_HID + m] = f2bf(acc[p] * dinv[rr]);
    }
}

// ---------------- gather layer 1: g2 = bf16( dinv * relu( dinv*(g1[self]+sum g1[in]) + b1 ) ) ----------------
// rows are 8 dwords (bf16x2); 8 subs x 8 lanes; unroll 4 -> 32 outstanding row loads/wave
__global__ __launch_bounds__(256) void k_gather1(const int* __restrict__ start,
                                                 const int* __restrict__ csr,
                                                 const uint_t* __restrict__ g1,
                                                 const float* __restrict__ dinv,
                                                 const float* __restrict__ b1,
                                                 uint_t* __restrict__ g2, int n) {
    int wid = threadIdx.x >> 6, lane = threadIdx.x & 63;
    int node = blockIdx.x * 4 + wid;
    if (node >= n) return;
    int fp = lane & 7, sub = lane >> 3;
    int s0 = start[node], s1 = start[node + 1];
    int len = s1 - s0;
    int q = (len + 7) >> 3;
    int e = s0 + sub * q;
    int end = min(e + q, s1);
    float l0 = 0.f, h0 = 0.f, l1 = 0.f, h1 = 0.f, l2 = 0.f, h2 = 0.f, l3 = 0.f, h3 = 0.f;
    for (; e + 4 <= end; e += 4) {
        int r0 = csr[e], r1 = csr[e + 1], r2 = csr[e + 2], r3 = csr[e + 3];
        uint_t v0 = g1[r0 * 8 + fp], v1 = g1[r1 * 8 + fp];
        uint_t v2 = g1[r2 * 8 + fp], v3 = g1[r3 * 8 + fp];
        l0 += lof(v0); h0 += hif(v0);
        l1 += lof(v1); h1 += hif(v1);
        l2 += lof(v2); h2 += hif(v2);
        l3 += lof(v3); h3 += hif(v3);
    }
    for (; e < end; ++e) {
        uint_t v = g1[csr[e] * 8 + fp];
        l0 += lof(v); h0 += hif(v);
    }
    float alo = (l0 + l1) + (l2 + l3);
    float ahi = (h0 + h1) + (h2 + h3);
    alo += __shfl_xor(alo, 8);  ahi += __shfl_xor(ahi, 8);
    alo += __shfl_xor(alo, 16); ahi += __shfl_xor(ahi, 16);
    alo += __shfl_xor(alo, 32); ahi += __shfl_xor(ahi, 32);
    uint_t sv = g1[(size_t)node * 8 + fp];     // self-loop
    alo += lof(sv); ahi += hif(sv);
    float di = dinv[node];
    const float2* b1v = (const float2*)b1;
    float2 bb = b1v[fp];
    float hlo = fmaxf(di * alo + bb.x, 0.f) * di;
    float hhi = fmaxf(di * ahi + bb.y, 0.f) * di;
    if (sub == 0) {
        unsigned pk;
        asm("v_cvt_pk_bf16_f32 %0, %1, %2" : "=v"(pk) : "v"(hlo), "v"(hhi));
        g2[(size_t)node * 8 + fp] = pk;
    }
}

// ---------------- gather layer 2 fused with W2 + bias + log_softmax ----------------
__global__ __launch_bounds__(256) void k_gather2f(const int* __restrict__ start,
                                                  const int* __restrict__ csr,
                                                  const uint_t* __restrict__ g2,
                                                  const float* __restrict__ dinv,
                                                  const float* __restrict__ W2,
                                                  const float* __restrict__ b2,
                                                  float* __restrict__ out, int n) {
    int wid = threadIdx.x >> 6, lane = threadIdx.x & 63;
    int node = blockIdx.x * 4 + wid;
    if (node >= n) return;
    int fp = lane & 7, sub = lane >> 3;
    int j = (lane < F_OUT) ? lane : 0;

    float w2c[F_HID];
#pragma unroll
    for (int k = 0; k < F_HID; ++k) w2c[k] = W2[k * F_OUT + j];
    float bj = b2[j];

    int s0 = start[node], s1 = start[node + 1];
    int len = s1 - s0;
    int q = (len + 7) >> 3;
    int e = s0 + sub * q;
    int end = min(e + q, s1);
    float l0 = 0.f, h0 = 0.f, l1 = 0.f, h1 = 0.f, l2 = 0.f, h2 = 0.f, l3 = 0.f, h3 = 0.f;
    for (; e + 4 <= end; e += 4) {
        int r0 = csr[e], r1 = csr[e + 1], r2 = csr[e + 2], r3 = csr[e + 3];
        uint_t v0 = g2[r0 * 8 + fp], v1 = g2[r1 * 8 + fp];
        uint_t v2 = g2[r2 * 8 + fp], v3 = g2[r3 * 8 + fp];
        l0 += lof(v0); h0 += hif(v0);
        l1 += lof(v1); h1 += hif(v1);
        l2 += lof(v2); h2 += hif(v2);
        l3 += lof(v3); h3 += hif(v3);
    }
    for (; e < end; ++e) {
        uint_t v = g2[csr[e] * 8 + fp];
        l0 += lof(v); h0 += hif(v);
    }
    float alo = (l0 + l1) + (l2 + l3);
    float ahi = (h0 + h1) + (h2 + h3);
    alo += __shfl_xor(alo, 8);  ahi += __shfl_xor(ahi, 8);
    alo += __shfl_xor(alo, 16); ahi += __shfl_xor(ahi, 16);
    alo += __shfl_xor(alo, 32); ahi += __shfl_xor(ahi, 32);
    uint_t sv = g2[(size_t)node * 8 + fp];     // self-loop
    alo += lof(sv); ahi += hif(sv);
    float di = dinv[node];
    float a_lo = di * alo;   // a[2*fp]
    float a_hi = di * ahi;   // a[2*fp+1]

    float o = bj;
#pragma unroll
    for (int k = 0; k < F_HID; k += 2) {
        o += __shfl(a_lo, k >> 1) * w2c[k] + __shfl(a_hi, k >> 1) * w2c[k + 1];
    }

    float mo = (lane < F_OUT) ? o : -3.4e38f;
#pragma unroll
    for (int off = 32; off; off >>= 1) mo = fmaxf(mo, __shfl_xor(mo, off));
    float ev = (lane < F_OUT) ? __expf(o - mo) : 0.f;
    float sv2 = ev;
#pragma unroll
    for (int off = 32; off; off >>= 1) sv2 += __shfl_xor(sv2, off);
    float lse = mo + __logf(sv2);
    if (lane < F_OUT) out[(size_t)node * F_OUT + lane] = o - lse;
}

// ---------------- launcher ----------------

extern "C" void kernel_launch(void* const* d_in, const int* in_sizes, int n_in,
                              void* d_out, int out_size, void* d_ws, size_t ws_size,
                              hipStream_t stream) {
    const float* x  = (const float*)d_in[0];
    const int*   ei = (const int*)d_in[1];
    const float* W1 = (const float*)d_in[2];
    const float* b1 = (const float*)d_in[3];
    const float* W2 = (const float*)d_in[4];
    const float* b2 = (const float*)d_in[5];
    float* out = (float*)d_out;

    const int N = out_size / F_OUT;       // 100000
    const int E = in_sizes[1] / 2;        // 3200000
    const int* row = ei;                  // sources
    const int* col = ei + E;              // targets

    const int NBUCK = (N + 511) >> 9;     // 196
    const int NWGE  = (E + CH - 1) / CH;  // 391
    const int tiles = (N + 15) / 16;
    const int nbT   = (tiles + 3) / 4;
    const int nbG   = (N + 3) / 4;

    // workspace layout
    int* bstart   = (int*)d_ws;                 // 260 (NBUCK+1 used)
    int* bcur     = bstart + 260;               // 256
    int* bhall    = bcur + 256;                 // NWGE*256
    int* start    = bhall + NWGE * 256;         // N+4
    int* csr      = start + N + 4;              // E
    int* pairs    = csr + E;                    // E
    float* dinv   = (float*)(pairs + E);        // N
    uint_t* g1    = (uint_t*)(dinv + N);        // 8N dwords (bf16x2 rows)
    uint_t* g2    = g1 + (size_t)N * 8;         // 8N dwords

    k_bhist<<<NWGE, 1024, 0, stream>>>(col, bhall, E);
    k_bscan2<<<1, 256, 0, stream>>>(bhall, bstart, bcur, NWGE);
    k_bscatter<<<NWGE, 1024, 0, stream>>>(row, col, bcur, pairs, E);
    k_build<<<NBUCK, 1024, 0, stream>>>(bstart, pairs, start, csr, dinv, N, E);

    k_xw1<<<nbT, 256, 0, stream>>>(x, W1, dinv, (ushort_t*)g1, tiles);

    k_gather1<<<nbG, 256, 0, stream>>>(start, csr, g1, dinv, b1, g2, N);
    k_gather2f<<<nbG, 256, 0, stream>>>(start, csr, g2, dinv, W2, b2, out, N);
}